// Round 19
// baseline (136.888 us; speedup 1.0000x reference)
//
#include <hip/hip_runtime.h>
#include <cstdint>

#define U_NUM 50000
#define F_NUM 20000
#define N_NUM 70000
#define D_EMB 128
#define THRESH 0.3f
#define BAND 0.02f

typedef _Float16 half8 __attribute__((ext_vector_type(8)));
typedef float f32x4 __attribute__((ext_vector_type(4)));
typedef unsigned short u16x8 __attribute__((ext_vector_type(8)));

#define NBT_U ((U_NUM + 63) / 64)   // 782
#define NBT_F ((F_NUM + 63) / 64)   // 313

// async 16B global -> LDS
__device__ __forceinline__ void gl_lds16(const void* g, void* l)
{
    __builtin_amdgcn_global_load_lds(
        (const __attribute__((address_space(1))) unsigned int*)g,
        (__attribute__((address_space(3))) unsigned int*)l, 16, 0, 0);
}

// ============ pre-convert weights to SINGLE fp16 plane (transposed [n][k]) + zero ============
// dst (ushort): W1u [128n][256k] @0; W1f @32768; Wq [128n][128k] @65536; Wk @81920. total 98304
__global__ void presplit_zero(const float* __restrict__ Wu, const float* __restrict__ Wf,
                              const float* __restrict__ Wq, const float* __restrict__ Wk,
                              unsigned short* __restrict__ dst,
                              int* __restrict__ cnt, int* __restrict__ cursor,
                              int* __restrict__ bcount)
{
    int i = blockIdx.x * 256 + threadIdx.x;
    if (i == 0) *bcount = 0;
    if (i < N_NUM) { cnt[i] = 0; cursor[i] = 0; }
    if (i >= 98304) return;
    float a; size_t d;
    if (i < 32768) {
        int n = i >> 8, k = i & 255;
        a = Wu[k * 128 + n]; d = (size_t)n * 256 + k;
    } else if (i < 65536) {
        int j = i - 32768; int n = j >> 8, k = j & 255;
        a = Wf[k * 128 + n]; d = 32768 + (size_t)n * 256 + k;
    } else if (i < 81920) {
        int j = i - 65536; int n = j >> 7, k = j & 127;
        a = Wq[k * 128 + n]; d = 65536 + (size_t)n * 128 + k;
    } else {
        int j = i - 81920; int n = j >> 7, k = j & 127;
        a = Wk[k * 128 + n]; d = 81920 + (size_t)n * 128 + k;
    }
    dst[d] = __builtin_bit_cast(unsigned short, (_Float16)a);
}

// ============ FUSED projection, single-fp16 bulk: QKh = fp16(relu(A@W1+b1)@W2) ============
// 64-row blocks (grid 1095), 4 waves x 16 rows, full 128 cols.
// LDS 48KB -> 3 blocks/CU: A f32 8KB dbuf; W 8KB dbuf (single plane); E fp16 16KB.
__global__ __launch_bounds__(256, 3)
void fused_gemm(const float* __restrict__ uf, const float* __restrict__ ff,
                const unsigned short* __restrict__ Wsp,
                const float* __restrict__ bu, const float* __restrict__ bfo,
                unsigned short* __restrict__ QKh)
{
    __shared__ char lds[49152];  // A: [0,16384) dbuf 8KB; W: [16384,32768) dbuf 8KB; E: [32768,49152)

    const int bid = blockIdx.x;
    const bool isU = bid < NBT_U;
    const int rt = isU ? bid : bid - NBT_U;
    const int Mloc = isU ? U_NUM : F_NUM;
    const int combBase = isU ? 0 : U_NUM;
    const float* A  = isU ? uf : ff;
    const float* b1 = isU ? bu : bfo;
    const unsigned short* W1 = Wsp + (isU ? 0 : 32768);
    const unsigned short* W2 = Wsp + (isU ? 65536 : 81920);

    const int tid = threadIdx.x;
    const int w  = tid >> 6;
    const int l  = tid & 63;
    const int lm = l & 15;
    const int lq = l >> 4;

    auto stageA = [&](int b, int kc) {
        // A tile: 64 rows x 32 k f32 (8 KB), 16B-chunk ^= row&7
#pragma unroll
        for (int j = 0; j < 2; ++j) {
            int off = j * 4096 + tid * 16;
            int row = off >> 7;
            int ch  = (off & 127) >> 4;
            int gch = ch ^ (row & 7);
            int gr  = min(rt * 64 + row, Mloc - 1);
            const float* src = A + (size_t)gr * 256 + kc * 32 + gch * 4;
            gl_lds16(src, lds + b * 8192 + j * 4096 + w * 1024);
        }
    };
    auto stageW1 = [&](int b, int kc) {
        // W1 tile: 128 n x 32 k fp16 (8 KB, single plane), chunk ^= (n>>1)&3
        {
            int off = tid * 16;              // wave-uniform base progression? per-thread 16B -> 4KB/128thr... need 8KB/256thr = 32B each
        }
#pragma unroll
        for (int j = 0; j < 2; ++j) {
            int off = j * 4096 + tid * 16;
            int n   = off >> 6;
            int ch  = (off & 63) >> 4;
            int gch = ch ^ ((n >> 1) & 3);
            const unsigned short* src = W1 + (size_t)n * 256 + kc * 32 + gch * 8;
            gl_lds16(src, lds + 16384 + b * 4096 + j * 4096 + w * 1024);
        }
    };
    auto stageW2 = [&](int b, int kc) {
#pragma unroll
        for (int j = 0; j < 2; ++j) {
            int off = j * 4096 + tid * 16;
            int n   = off >> 6;
            int ch  = (off & 63) >> 4;
            int gch = ch ^ ((n >> 1) & 3);
            const unsigned short* src = W2 + (size_t)n * 128 + kc * 32 + gch * 8;
            gl_lds16(src, lds + 16384 + b * 4096 + j * 4096 + w * 1024);
        }
    };
    // NOTE: W dbuf is 2 x 8KB?  [16384,32768) = 16KB; buffer b at 16384 + b*8192.
    // The lambdas above map j*4096 within an 8KB buffer: fix base accordingly.

    (void)stageW1; (void)stageW2;
    auto stW1 = [&](int b, int kc) {
#pragma unroll
        for (int j = 0; j < 2; ++j) {
            int off = j * 4096 + tid * 16;
            int n   = off >> 6;
            int ch  = (off & 63) >> 4;
            int gch = ch ^ ((n >> 1) & 3);
            const unsigned short* src = W1 + (size_t)n * 256 + kc * 32 + gch * 8;
            gl_lds16(src, lds + 16384 + b * 8192 + off - (off & 15));
        }
    };
    auto stW2 = [&](int b, int kc) {
#pragma unroll
        for (int j = 0; j < 2; ++j) {
            int off = j * 4096 + tid * 16;
            int n   = off >> 6;
            int ch  = (off & 63) >> 4;
            int gch = ch ^ ((n >> 1) & 3);
            const unsigned short* src = W2 + (size_t)n * 128 + kc * 32 + gch * 8;
            gl_lds16(src, lds + 16384 + b * 8192 + off - (off & 15));
        }
    };

    // ---- stage 1: E = relu(A @ W1 + b1) ----
    stageA(0, 0); stW1(0, 0);
    __syncthreads();

    f32x4 acc1[8];
#pragma unroll
    for (int j = 0; j < 8; j++) acc1[j] = (f32x4)0.f;

    int buf = 0;
#pragma unroll
    for (int kc = 0; kc < 8; ++kc) {
        if (kc < 7) { stageA(buf ^ 1, kc + 1); stW1(buf ^ 1, kc + 1); }

        half8 ah;
        {
            int lr = w * 16 + lm;
            int r7 = lr & 7;
            const float* basep = (const float*)(lds + buf * 8192 + lr * 128);
            f32x4 x0 = *(const f32x4*)(basep + ((((lq * 2)    ) ^ r7) << 2));
            f32x4 x1 = *(const f32x4*)(basep + ((((lq * 2) + 1) ^ r7) << 2));
            float v[8] = {x0[0], x0[1], x0[2], x0[3], x1[0], x1[1], x1[2], x1[3]};
#pragma unroll
            for (int i = 0; i < 8; i++) ah[i] = (_Float16)v[i];
        }
#pragma unroll
        for (int cb = 0; cb < 8; ++cb) {
            int n = cb * 16 + lm;
            int wc = lq ^ ((n >> 1) & 3);
            half8 bh = *(const half8*)(lds + 16384 + buf * 8192 + n * 64 + wc * 16);
            acc1[cb] = __builtin_amdgcn_mfma_f32_16x16x32_f16(ah, bh, acc1[cb], 0, 0, 0);
        }
        __syncthreads();
        buf ^= 1;
    }

    // ---- E = fp16(relu(acc1 + b1)) -> LDS [32768,49152): 64 rows x 128 fp16, chunk ^= row&7 ----
    stW2(0, 0);   // W buffers free after loop's final barrier
    {
        unsigned short* E = (unsigned short*)(lds + 32768);
#pragma unroll
        for (int cb = 0; cb < 8; ++cb) {
            const int col = cb * 16 + lm;
            const float bb = b1[col];
#pragma unroll
            for (int rg = 0; rg < 4; ++rg) {
                const int row = w * 16 + lq * 4 + rg;
                float e = fmaxf(acc1[cb][rg] + bb, 0.f);
                int chn = (col >> 3) ^ (row & 7);          // 16B chunk (8 fp16)
                E[row * 128 + chn * 8 + (col & 7)] = __builtin_bit_cast(unsigned short, (_Float16)e);
            }
        }
    }
    __syncthreads();   // drain W2(0); E rows are wave-private (written+read by same wave)

    // ---- stage 2: Q = E @ W2 ----
    f32x4 acc2[8];
#pragma unroll
    for (int j = 0; j < 8; j++) acc2[j] = (f32x4)0.f;

    buf = 0;
#pragma unroll
    for (int kc = 0; kc < 4; ++kc) {
        if (kc < 3) stW2(buf ^ 1, kc + 1);

        half8 ah;
        {
            const int row = w * 16 + lm;
            const int r7 = row & 7;
            const int c0 = (kc * 4 + lq) ^ r7;             // chunk in 16-chunk row
            ah = *(const half8*)((const unsigned short*)(lds + 32768) + row * 128 + c0 * 8);
        }
#pragma unroll
        for (int cb = 0; cb < 8; ++cb) {
            int n = cb * 16 + lm;
            int wc = lq ^ ((n >> 1) & 3);
            half8 bh = *(const half8*)(lds + 16384 + buf * 8192 + n * 64 + wc * 16);
            acc2[cb] = __builtin_amdgcn_mfma_f32_16x16x32_f16(ah, bh, acc2[cb], 0, 0, 0);
        }
        __syncthreads();
        buf ^= 1;
    }

    // ---- epilogue: store QKh fp16 only ----
#pragma unroll
    for (int cb = 0; cb < 8; ++cb) {
        const int col = cb * 16 + lm;
#pragma unroll
        for (int rg = 0; rg < 4; ++rg) {
            int lr = rt * 64 + w * 16 + lq * 4 + rg;
            if (lr < Mloc) {
                size_t rr = (size_t)(combBase + lr);
                QKh[rr * 128 + col] = __builtin_bit_cast(unsigned short, (_Float16)acc2[cb][rg]);
            }
        }
    }
}

// ============ per-edge mask (fp16 path) + borderline compaction ============
__global__ __launch_bounds__(256)
void edge_kernel(const int* __restrict__ ei, int Edir,
                 const unsigned short* __restrict__ QKh,
                 const float* __restrict__ cwts,
                 float* __restrict__ maskf, int* __restrict__ cnt,
                 int* __restrict__ blist, int* __restrict__ bcount, int Eund)
{
    int gid = blockIdx.x * 256 + threadIdx.x;
    int e = gid >> 3;
    if (e >= Eund) return;
    int sub = gid & 7;
    int row = ei[e];
    int col = ei[Edir + e];
    row = min(max(row, 0), N_NUM - 1);
    col = min(max(col, 0), N_NUM - 1);
    int u  = (row < U_NUM) ? row : col;
    int fg = (row < U_NUM) ? col : row;
    u = min(max(u, 0), U_NUM - 1);
    int f = min(max(fg - U_NUM, 0), F_NUM - 1);
    const size_t qrow = (size_t)u * D_EMB;
    const size_t krow = (size_t)(U_NUM + f) * D_EMB;

    const unsigned short* qh = QKh + qrow + sub * 16;
    const unsigned short* kh = QKh + krow + sub * 16;
    u16x8 qa = *(const u16x8*)(qh);
    u16x8 qb = *(const u16x8*)(qh + 8);
    u16x8 ka = *(const u16x8*)(kh);
    u16x8 kb = *(const u16x8*)(kh + 8);
    float dot = 0.f, qq = 0.f, kk = 0.f;
#pragma unroll
    for (int i = 0; i < 8; i++) {
        float qv = (float)__builtin_bit_cast(_Float16, (unsigned short)qa[i]);
        float kv = (float)__builtin_bit_cast(_Float16, (unsigned short)ka[i]);
        dot += qv * kv; qq += qv * qv; kk += kv * kv;
    }
#pragma unroll
    for (int i = 0; i < 8; i++) {
        float qv = (float)__builtin_bit_cast(_Float16, (unsigned short)qb[i]);
        float kv = (float)__builtin_bit_cast(_Float16, (unsigned short)kb[i]);
        dot += qv * kv; qq += qv * qv; kk += kv * kv;
    }
    dot += __shfl_xor(dot, 1);
    qq  += __shfl_xor(qq, 1);
    kk  += __shfl_xor(kk, 1);
    float denom = sqrtf(qq) * sqrtf(kk) + 1e-8f;
    float sim = dot / denom;
    float s = sim + __shfl_xor(sim, 2);
    s += __shfl_xor(s, 4);
    float mean = s * 0.25f;

    float mf = (mean > THRESH) ? 1.f : 0.f;
    float cw0 = cwts[0], cw1 = cwts[1];
    float mx = fmaxf(cw0, cw1);
    float e0 = expf(cw0 - mx), e1 = expf(cw1 - mx);
    float inv = 1.f / (e0 + e1);
    float fused = e0 * inv + (e1 * inv) * mf;
    float em = (fused > 0.5f) ? 1.f : 0.f;

    if (sub == 0) {
        maskf[e] = em;
        if (em != 0.f) {
            atomicAdd(&cnt[row], 1);
            atomicAdd(&cnt[col], 1);
        }
        if (fabsf(mean - THRESH) < BAND) {
            int p = atomicAdd(bcount, 1);
            blist[p] = e;
        }
    }
}

// ============ exact recheck from f32 inputs (one wave per borderline edge) ============
__global__ __launch_bounds__(256)
void recheck_kernel(const int* __restrict__ ei, int Edir,
                    const int* __restrict__ blist, const int* __restrict__ bcount,
                    const float* __restrict__ uf, const float* __restrict__ ff,
                    const float* __restrict__ Wu, const float* __restrict__ bu,
                    const float* __restrict__ Wf, const float* __restrict__ bfo,
                    const float* __restrict__ Wq, const float* __restrict__ Wk,
                    const float* __restrict__ cwts,
                    float* __restrict__ maskf, int* __restrict__ cnt)
{
    __shared__ float Esh[4][128];
    const int w = threadIdx.x >> 6;
    const int l = threadIdx.x & 63;
    const int nwaves = gridDim.x * 4;
    int widx = blockIdx.x * 4 + w;
    const int total = *bcount;

    for (int i = widx; i < total; i += nwaves) {
        int e = blist[i];
        int row = ei[e], col = ei[Edir + e];
        row = min(max(row, 0), N_NUM - 1);
        col = min(max(col, 0), N_NUM - 1);
        int u  = (row < U_NUM) ? row : col;
        int fg = (row < U_NUM) ? col : row;
        u = min(max(u, 0), U_NUM - 1);
        int f = min(max(fg - U_NUM, 0), F_NUM - 1);

        float q0, q1, k0v, k1v;
        {   // user row exact
            const float* a = uf + (size_t)u * 256;
            float e0 = 0.f, e1 = 0.f;
            for (int k = 0; k < 256; ++k) {
                float av = a[k];
                e0 += av * Wu[k * 128 + l];
                e1 += av * Wu[k * 128 + 64 + l];
            }
            e0 = fmaxf(e0 + bu[l], 0.f);
            e1 = fmaxf(e1 + bu[64 + l], 0.f);
            Esh[w][l] = e0; Esh[w][64 + l] = e1;
            float s0 = 0.f, s1 = 0.f;
            for (int k = 0; k < 128; ++k) {
                float ev = Esh[w][k];
                s0 += ev * Wq[k * 128 + l];
                s1 += ev * Wq[k * 128 + 64 + l];
            }
            q0 = s0; q1 = s1;
        }
        {   // food row exact
            const float* a = ff + (size_t)f * 256;
            float e0 = 0.f, e1 = 0.f;
            for (int k = 0; k < 256; ++k) {
                float av = a[k];
                e0 += av * Wf[k * 128 + l];
                e1 += av * Wf[k * 128 + 64 + l];
            }
            e0 = fmaxf(e0 + bfo[l], 0.f);
            e1 = fmaxf(e1 + bfo[64 + l], 0.f);
            Esh[w][l] = e0; Esh[w][64 + l] = e1;
            float s0 = 0.f, s1 = 0.f;
            for (int k = 0; k < 128; ++k) {
                float ev = Esh[w][k];
                s0 += ev * Wk[k * 128 + l];
                s1 += ev * Wk[k * 128 + 64 + l];
            }
            k0v = s0; k1v = s1;
        }
        // per-head reductions: lane l holds cols l (head l>>5) and l+64 (head 2+(l>>5))
        float d0 = q0 * k0v, d1 = q1 * k1v;
        float qa = q0 * q0, qb = q1 * q1, ka = k0v * k0v, kb = k1v * k1v;
#pragma unroll
        for (int off = 1; off < 32; off <<= 1) {
            d0 += __shfl_xor(d0, off); d1 += __shfl_xor(d1, off);
            qa += __shfl_xor(qa, off); qb += __shfl_xor(qb, off);
            ka += __shfl_xor(ka, off); kb += __shfl_xor(kb, off);
        }
        float sA = d0 / (sqrtf(qa) * sqrtf(ka) + 1e-8f);
        float sB = d1 / (sqrtf(qb) * sqrtf(kb) + 1e-8f);
        float s = sA + sB;
        s += __shfl_xor(s, 32);
        float mean = s * 0.25f;

        if (l == 0) {
            float mf = (mean > THRESH) ? 1.f : 0.f;
            float cw0 = cwts[0], cw1 = cwts[1];
            float mx = fmaxf(cw0, cw1);
            float e0 = expf(cw0 - mx), e1 = expf(cw1 - mx);
            float inv = 1.f / (e0 + e1);
            float fusedv = e0 * inv + (e1 * inv) * mf;
            bool em = fusedv > 0.5f;
            bool old = maskf[e] > 0.5f;
            if (em != old) {
                maskf[e] = em ? 1.f : 0.f;
                int d = em ? 1 : -1;
                atomicAdd(&cnt[row], d);
                atomicAdd(&cnt[col], d);
            }
        }
    }
}

// ============ exclusive scan over cnt[N] (3 kernels) ============
__global__ void scan_part(const int* __restrict__ cnt, int* __restrict__ part, int n)
{
    __shared__ int sd[256];
    int b = blockIdx.x, t = threadIdx.x;
    int base = b * 1024;
    int s = 0;
#pragma unroll
    for (int j = 0; j < 4; j++) {
        int idx = base + t + j * 256;
        if (idx < n) s += cnt[idx];
    }
    sd[t] = s; __syncthreads();
    for (int d = 128; d > 0; d >>= 1) {
        if (t < d) sd[t] += sd[t + d];
        __syncthreads();
    }
    if (t == 0) part[b] = sd[0];
}

__global__ void scan_small(int* part, int nb)
{
    __shared__ int sd[256];
    int t = threadIdx.x;
    sd[t] = (t < nb) ? part[t] : 0;
    __syncthreads();
    for (int d = 1; d < 256; d <<= 1) {
        int x = (t >= d) ? sd[t - d] : 0;
        __syncthreads();
        sd[t] += x;
        __syncthreads();
    }
    if (t < nb) part[t] = (t > 0) ? sd[t - 1] : 0;
}

__global__ void scan_final(const int* __restrict__ cnt, const int* __restrict__ part,
                           int* __restrict__ offs, int n)
{
    __shared__ int sd[256];
    int b = blockIdx.x, t = threadIdx.x;
    int base = b * 1024 + t * 4;
    int v[4]; int s = 0;
#pragma unroll
    for (int j = 0; j < 4; j++) {
        int idx = base + j;
        v[j] = (idx < n) ? cnt[idx] : 0;
        s += v[j];
    }
    sd[t] = s; __syncthreads();
    for (int d = 1; d < 256; d <<= 1) {
        int x = (t >= d) ? sd[t - d] : 0;
        __syncthreads();
        sd[t] += x;
        __syncthreads();
    }
    int prefix = part[b] + ((t > 0) ? sd[t - 1] : 0);
#pragma unroll
    for (int j = 0; j < 4; j++) {
        int idx = base + j;
        if (idx < n) offs[idx] = prefix;
        prefix += v[j];
    }
}

// ============ CSR scatter ============
__global__ void scatter_kernel(const int* __restrict__ ei, int Edir,
                               const float* __restrict__ maskf,
                               const int* __restrict__ cnt, const int* __restrict__ offs,
                               int* __restrict__ cursor,
                               int* __restrict__ cnbr, float* __restrict__ cwA, int Eund)
{
    int e = blockIdx.x * 256 + threadIdx.x;
    if (e >= Eund) return;
    if (maskf[e] == 0.f) return;
    int row = ei[e], col = ei[Edir + e];
    row = min(max(row, 0), N_NUM - 1);
    col = min(max(col, 0), N_NUM - 1);
    float w = 1.0f / sqrtf((float)cnt[row] * (float)cnt[col]);
    int p1 = offs[row] + atomicAdd(&cursor[row], 1);
    cnbr[p1] = col; cwA[p1] = w;
    int p2 = offs[col] + atomicAdd(&cursor[col], 1);
    cnbr[p2] = row; cwA[p2] = w;
}

// ============ propagation ============
template<int MODE>
__global__ __launch_bounds__(256)
void prop(const int* __restrict__ offs, const int* __restrict__ cnt,
          const int* __restrict__ cnbr, const float* __restrict__ cwA,
          const float* __restrict__ xin,
          const float* __restrict__ ue, const float* __restrict__ ie,
          const float* __restrict__ x1b, float* __restrict__ xout,
          float* __restrict__ tail)
{
    int wid = (blockIdx.x << 2) + (threadIdx.x >> 6);
    if (wid >= N_NUM) return;
    int lane = threadIdx.x & 63;
    int num = cnt[wid];
    if (MODE != 2 && num == 0) return;
    int start = (num > 0) ? offs[wid] : 0;
    float ax = 0.f, ay = 0.f;

    auto srcp = [&](int c) -> const float* {
        if (MODE == 0)
            return (c < U_NUM) ? (ue + (size_t)c * D_EMB) : (ie + (size_t)(c - U_NUM) * D_EMB);
        else
            return xin + (size_t)c * D_EMB;
    };

    int j = 0;
    for (; j + 4 <= num; j += 4) {
        int c0i = cnbr[start + j],     c1i = cnbr[start + j + 1];
        int c2i = cnbr[start + j + 2], c3i = cnbr[start + j + 3];
        float w0 = cwA[start + j],     w1 = cwA[start + j + 1];
        float w2 = cwA[start + j + 2], w3 = cwA[start + j + 3];
        float2 v0 = *(const float2*)(srcp(c0i) + lane * 2);
        float2 v1 = *(const float2*)(srcp(c1i) + lane * 2);
        float2 v2 = *(const float2*)(srcp(c2i) + lane * 2);
        float2 v3 = *(const float2*)(srcp(c3i) + lane * 2);
        ax += w0 * v0.x; ay += w0 * v0.y;
        ax += w1 * v1.x; ay += w1 * v1.y;
        ax += w2 * v2.x; ay += w2 * v2.y;
        ax += w3 * v3.x; ay += w3 * v3.y;
    }
    for (; j < num; ++j) {
        int c = cnbr[start + j]; float w = cwA[start + j];
        float2 v = *(const float2*)(srcp(c) + lane * 2);
        ax += w * v.x; ay += w * v.y;
    }

    size_t o = (size_t)wid * D_EMB + lane * 2;
    if (MODE == 2) {
        const float* x0p = (wid < U_NUM) ? (ue + (size_t)wid * D_EMB)
                                         : (ie + (size_t)(wid - U_NUM) * D_EMB);
        float2 x0v = *(const float2*)(x0p + lane * 2);
        *(float2*)(tail + o) = x0v;                     // embed copy (output tail)
        float ox, oy;
        if (num == 0) {
            ox = x0v.x * 0.25f; oy = x0v.y * 0.25f;
        } else {
            float2 x1v = *(const float2*)(x1b + o);
            float2 x2v = *(const float2*)(xin + o);
            ox = ((x0v.x + x1v.x) + x2v.x + ax) * 0.25f;
            oy = ((x0v.y + x1v.y) + x2v.y + ay) * 0.25f;
        }
        *(float2*)(xout + o) = make_float2(ox, oy);
    } else {
        *(float2*)(xout + o) = make_float2(ax, ay);
    }
}

// ============ launcher ============
extern "C" void kernel_launch(void* const* d_in, const int* in_sizes, int n_in,
                              void* d_out, int out_size, void* d_ws, size_t ws_size,
                              hipStream_t stream)
{
    const float* user_feat  = (const float*)d_in[0];
    const float* food_feat  = (const float*)d_in[1];
    const int*   ei         = (const int*)d_in[2];
    const float* W_user     = (const float*)d_in[3];
    const float* b_user     = (const float*)d_in[4];
    const float* W_food     = (const float*)d_in[5];
    const float* b_food     = (const float*)d_in[6];
    const float* Wq         = (const float*)d_in[7];
    const float* Wk         = (const float*)d_in[8];
    const float* cwts       = (const float*)d_in[9];
    const float* user_embed = (const float*)d_in[10];
    const float* item_embed = (const float*)d_in[11];

    const int Edir = in_sizes[2] / 2;   // 1.2M directed edges
    const int Eund = Edir / 2;          // 600K undirected ([u,f] || [f,u])

    char* ws = (char*)d_ws;
    size_t off = 0;
    auto alloc = [&](size_t nb) { size_t o = off; off += (nb + 255) & ~(size_t)255; return o; };

    float* xA    = (float*)(ws + alloc((size_t)N_NUM * D_EMB * 4));
    float* xB    = (float*)(ws + alloc((size_t)N_NUM * D_EMB * 4));
    unsigned short* QKh = (unsigned short*)(ws + alloc((size_t)N_NUM * D_EMB * 2));
    float* maskf = (float*)(ws + alloc((size_t)Eund * 4));
    int*   cnt   = (int*)  (ws + alloc((size_t)N_NUM * 4));
    int*   offs  = (int*)  (ws + alloc((size_t)N_NUM * 4));
    int*   cursor= (int*)  (ws + alloc((size_t)N_NUM * 4));
    int*   cnbr  = (int*)  (ws + alloc((size_t)Edir * 4));
    float* cwA   = (float*)(ws + alloc((size_t)Edir * 4));
    int*   part  = (int*)  (ws + alloc((size_t)256 * 4));
    unsigned short* Wsp = (unsigned short*)(ws + alloc((size_t)98304 * 2));
    int*   blist = (int*)  (ws + alloc((size_t)Eund * 4));
    int*   bcount= (int*)  (ws + alloc(256));
    (void)ws_size; (void)n_in; (void)out_size;

    // 1) weights -> single fp16 plane; zero counters + bcount
    presplit_zero<<<384, 256, 0, stream>>>(W_user, W_food, Wq, Wk, Wsp, cnt, cursor, bcount);

    // 2) fused projection (single-fp16 bulk), writes QKh only
    fused_gemm<<<NBT_U + NBT_F, 256, 0, stream>>>(user_feat, food_feat, Wsp,
                                                  b_user, b_food, QKh);

    // 3) per-edge mask + degree counts + borderline compaction
    edge_kernel<<<(Eund * 8 + 255) / 256, 256, 0, stream>>>(ei, Edir, QKh, cwts,
                                                            maskf, cnt, blist, bcount, Eund);

    // 4) exact recheck of borderline edges from f32 inputs
    recheck_kernel<<<1024, 256, 0, stream>>>(ei, Edir, blist, bcount,
                                             user_feat, food_feat,
                                             W_user, b_user, W_food, b_food,
                                             Wq, Wk, cwts, maskf, cnt);

    // 5) exclusive scan of cnt -> offs
    int nb = (N_NUM + 1023) / 1024;
    scan_part <<<nb, 256, 0, stream>>>(cnt, part, N_NUM);
    scan_small<<<1, 256, 0, stream>>>(part, nb);
    scan_final<<<nb, 256, 0, stream>>>(cnt, part, offs, N_NUM);

    // 6) CSR scatter
    scatter_kernel<<<(Eund + 255) / 256, 256, 0, stream>>>(ei, Edir, maskf, cnt, offs,
                                                           cursor, cnbr, cwA, Eund);

    // 7) three LightGCN layers; last fuses epilogue + embeds tail copy
    int pb = (N_NUM + 3) / 4;
    float* tail = (float*)d_out + (size_t)N_NUM * D_EMB;
    prop<0><<<pb, 256, 0, stream>>>(offs, cnt, cnbr, cwA, nullptr, user_embed, item_embed,
                                    nullptr, xB, nullptr);
    prop<1><<<pb, 256, 0, stream>>>(offs, cnt, cnbr, cwA, xB, user_embed, item_embed,
                                    nullptr, xA, nullptr);
    prop<2><<<pb, 256, 0, stream>>>(offs, cnt, cnbr, cwA, xA, user_embed, item_embed,
                                    xB, (float*)d_out, tail);
}

// Round 20
// 128.337 us; speedup vs baseline: 1.0666x; 1.0666x over previous
//
#include <hip/hip_runtime.h>
#include <cstdint>

#define U_NUM 50000
#define F_NUM 20000
#define N_NUM 70000
#define D_EMB 128
#define THRESH 0.3f

typedef _Float16 half8 __attribute__((ext_vector_type(8)));
typedef float f32x4 __attribute__((ext_vector_type(4)));
typedef unsigned short u16x8 __attribute__((ext_vector_type(8)));

#define NBT_U ((U_NUM + 63) / 64)   // 782 row tiles (users)
#define NBT_F ((F_NUM + 63) / 64)   // 313 row tiles (foods)

// async 16B global -> LDS
__device__ __forceinline__ void gl_lds16(const void* g, void* l)
{
    __builtin_amdgcn_global_load_lds(
        (const __attribute__((address_space(1))) unsigned int*)g,
        (__attribute__((address_space(3))) unsigned int*)l, 16, 0, 0);
}

// ============ pre-split weights + zero counters ============
__global__ void presplit_zero(const float* __restrict__ Wu, const float* __restrict__ Wf,
                              const float* __restrict__ Wq, const float* __restrict__ Wk,
                              unsigned short* __restrict__ dst,
                              int* __restrict__ cnt, int* __restrict__ cursor)
{
    int i = blockIdx.x * 256 + threadIdx.x;
    if (i < N_NUM) { cnt[i] = 0; cursor[i] = 0; }
    if (i >= 98304) return;
    float a; size_t d; int pstride;
    if (i < 32768) {
        int n = i >> 8, k = i & 255;
        a = Wu[k * 128 + n]; d = (size_t)n * 256 + k; pstride = 32768;
    } else if (i < 65536) {
        int j = i - 32768; int n = j >> 8, k = j & 255;
        a = Wf[k * 128 + n]; d = 65536 + (size_t)n * 256 + k; pstride = 32768;
    } else if (i < 81920) {
        int j = i - 65536; int n = j >> 7, k = j & 127;
        a = Wq[k * 128 + n]; d = 131072 + (size_t)n * 128 + k; pstride = 16384;
    } else {
        int j = i - 81920; int n = j >> 7, k = j & 127;
        a = Wk[k * 128 + n]; d = 163840 + (size_t)n * 128 + k; pstride = 16384;
    }
    _Float16 c1 = (_Float16)a;            // RNE
    float r = a - (float)c1;
    _Float16 c2 = (_Float16)r;            // RNE
    dst[d]           = __builtin_bit_cast(unsigned short, c1);
    dst[d + pstride] = __builtin_bit_cast(unsigned short, c2);
}

// ============ split 8 f32 -> hi/lo fp16 fragments ============
__device__ __forceinline__ void split2v(const f32x4 x0, const f32x4 x1,
                                        half8& h, half8& lo)
{
    float v[8] = {x0[0], x0[1], x0[2], x0[3], x1[0], x1[1], x1[2], x1[3]};
#pragma unroll
    for (int i = 0; i < 8; i++) {
        _Float16 c1 = (_Float16)v[i];
        h[i] = c1;
        lo[i] = (_Float16)(v[i] - (float)c1);
    }
}

// ============ FUSED projection: Q = relu(A@W1+b1)@W2 (f32 + fp16 copy) ============
// 64-row blocks (grid 1095), 4 waves x 16 rows, full 128 cols.
// Stage 1: DMA staging (A 8KB + W1 16KB, dbuf, drain-at-barrier).
// E -> wave-private LDS (f32, XOR swizzle; no barrier needed) -- E never hits HBM.
// Stage 2: W2 16KB dbuf staging; E read from LDS.  LDS 80KB -> 2 blocks/CU.
__global__ __launch_bounds__(256, 2)
void fused_gemm(const float* __restrict__ uf, const float* __restrict__ ff,
                const unsigned short* __restrict__ Wsp,
                const float* __restrict__ bu, const float* __restrict__ bfo,
                float* __restrict__ Qo, unsigned short* __restrict__ QKh)
{
    __shared__ char lds[81920];  // A: [0,16384) dbuf 8KB; W: [16384,49152) dbuf 16KB; E: [49152,81920) 4x8KB

    const int bid = blockIdx.x;
    const bool isU = bid < NBT_U;
    const int rt = isU ? bid : bid - NBT_U;
    const int Mloc = isU ? U_NUM : F_NUM;
    const int combBase = isU ? 0 : U_NUM;
    const float* A  = isU ? uf : ff;
    const float* b1 = isU ? bu : bfo;
    const unsigned short* W1 = Wsp + (isU ? 0 : 65536);
    const unsigned short* W2 = Wsp + (isU ? 131072 : 163840);

    const int tid = threadIdx.x;
    const int w  = tid >> 6;
    const int l  = tid & 63;
    const int lm = l & 15;
    const int lq = l >> 4;

    auto stageA = [&](int b, int kc) {
        // A tile: 64 rows x 32 k f32 (8 KB), 16B-chunk ^= row&7
#pragma unroll
        for (int j = 0; j < 2; ++j) {
            int off = j * 4096 + tid * 16;
            int row = off >> 7;
            int ch  = (off & 127) >> 4;
            int gch = ch ^ (row & 7);
            int gr  = min(rt * 64 + row, Mloc - 1);
            const float* src = A + (size_t)gr * 256 + kc * 32 + gch * 4;
            gl_lds16(src, lds + b * 8192 + j * 4096 + w * 1024);
        }
    };
    auto stageW1 = [&](int b, int kc) {
        // W1 tile: 2 planes x 128 n x 32 k fp16 (16 KB), chunk ^= (n>>1)&3
#pragma unroll
        for (int j = 0; j < 4; ++j) {
            int off = w * 4096 + j * 1024 + l * 16;
            int p   = off >> 13;
            int n   = (off & 8191) >> 6;
            int ch  = (off & 63) >> 4;
            int gch = ch ^ ((n >> 1) & 3);
            const unsigned short* src = W1 + (size_t)p * 32768 + (size_t)n * 256 + kc * 32 + gch * 8;
            gl_lds16(src, lds + 16384 + b * 16384 + w * 4096 + j * 1024);
        }
    };
    auto stageW2 = [&](int b, int kc) {
        // W2 tile: 2 planes x 128 n x 32 k fp16 (16 KB), chunk ^= (n>>1)&3
#pragma unroll
        for (int j = 0; j < 4; ++j) {
            int off = w * 4096 + j * 1024 + l * 16;
            int p   = off >> 13;
            int n   = (off & 8191) >> 6;
            int ch  = (off & 63) >> 4;
            int gch = ch ^ ((n >> 1) & 3);
            const unsigned short* src = W2 + (size_t)p * 16384 + (size_t)n * 128 + kc * 32 + gch * 8;
            gl_lds16(src, lds + 16384 + b * 16384 + w * 4096 + j * 1024);
        }
    };

    // ---- stage 1: E = A @ W1 (bias/relu deferred to E-write) ----
    stageA(0, 0); stageW1(0, 0);
    __syncthreads();

    f32x4 acc1[8];
#pragma unroll
    for (int j = 0; j < 8; j++) acc1[j] = (f32x4)0.f;

    int buf = 0;
#pragma unroll
    for (int kc = 0; kc < 8; ++kc) {
        if (kc < 7) { stageA(buf ^ 1, kc + 1); stageW1(buf ^ 1, kc + 1); }

        half8 ah, al;
        {
            int lr = w * 16 + lm;
            int r7 = lr & 7;
            const float* basep = (const float*)(lds + buf * 8192 + lr * 128);
            f32x4 x0 = *(const f32x4*)(basep + ((((lq * 2)    ) ^ r7) << 2));
            f32x4 x1 = *(const f32x4*)(basep + ((((lq * 2) + 1) ^ r7) << 2));
            split2v(x0, x1, ah, al);
        }
#pragma unroll
        for (int cb = 0; cb < 8; ++cb) {
            int n = cb * 16 + lm;
            int wc = lq ^ ((n >> 1) & 3);
            const char* wbase = lds + 16384 + buf * 16384;
            half8 bh = *(const half8*)(wbase + n * 64 + wc * 16);
            half8 bl = *(const half8*)(wbase + 8192 + n * 64 + wc * 16);
            acc1[cb] = __builtin_amdgcn_mfma_f32_16x16x32_f16(al, bh, acc1[cb], 0, 0, 0);
            acc1[cb] = __builtin_amdgcn_mfma_f32_16x16x32_f16(ah, bl, acc1[cb], 0, 0, 0);
            acc1[cb] = __builtin_amdgcn_mfma_f32_16x16x32_f16(ah, bh, acc1[cb], 0, 0, 0);
        }
        __syncthreads();
        buf ^= 1;
    }

    // ---- E = relu(acc1 + b1) -> wave-private LDS (f32, 16B-chunk XOR swizzle) ----
    float* EW = (float*)(lds + 49152 + w * 8192);   // 16 rows x 128 f32
#pragma unroll
    for (int cb = 0; cb < 8; ++cb) {
        const int col = cb * 16 + lm;
        const float bb = b1[col];
#pragma unroll
        for (int rg = 0; rg < 4; ++rg) {
            const int row = lq * 4 + rg;            // 0..15
            float e = fmaxf(acc1[cb][rg] + bb, 0.f);
            EW[row * 128 + ((((col >> 2) ^ (row & 7)) << 2) | (col & 3))] = e;
        }
    }

    // ---- stage 2: Q = E @ W2 ----
    f32x4 acc2[8];
#pragma unroll
    for (int j = 0; j < 8; j++) acc2[j] = (f32x4)0.f;

    stageW2(0, 0);
    __syncthreads();
    buf = 0;
#pragma unroll
    for (int kc = 0; kc < 4; ++kc) {
        if (kc < 3) stageW2(buf ^ 1, kc + 1);

        half8 ah, al;
        {
            const int row = lm;                     // wave's 16 rows
            const int r7 = row & 7;
            const int c0 = kc * 8 + lq * 2;         // 16B-chunk index (0..31)
            f32x4 x0 = *(const f32x4*)(EW + row * 128 + (((c0    ) ^ r7) << 2));
            f32x4 x1 = *(const f32x4*)(EW + row * 128 + (((c0 + 1) ^ r7) << 2));
            split2v(x0, x1, ah, al);
        }
#pragma unroll
        for (int cb = 0; cb < 8; ++cb) {
            int n = cb * 16 + lm;
            int wc = lq ^ ((n >> 1) & 3);
            const char* wbase = lds + 16384 + buf * 16384;
            half8 bh = *(const half8*)(wbase + n * 64 + wc * 16);
            half8 bl = *(const half8*)(wbase + 8192 + n * 64 + wc * 16);
            acc2[cb] = __builtin_amdgcn_mfma_f32_16x16x32_f16(al, bh, acc2[cb], 0, 0, 0);
            acc2[cb] = __builtin_amdgcn_mfma_f32_16x16x32_f16(ah, bl, acc2[cb], 0, 0, 0);
            acc2[cb] = __builtin_amdgcn_mfma_f32_16x16x32_f16(ah, bh, acc2[cb], 0, 0, 0);
        }
        __syncthreads();
        buf ^= 1;
    }

    // ---- epilogue: store Q f32 + fp16 copy ----
#pragma unroll
    for (int cb = 0; cb < 8; ++cb) {
        const int col = cb * 16 + lm;
#pragma unroll
        for (int rg = 0; rg < 4; ++rg) {
            int lr = rt * 64 + w * 16 + lq * 4 + rg;
            if (lr < Mloc) {
                size_t rr = (size_t)(combBase + lr);
                float v = acc2[cb][rg];
                Qo[rr * 128 + col] = v;
                QKh[rr * 128 + col] = __builtin_bit_cast(unsigned short, (_Float16)v);
            }
        }
    }
}

// ============ per-edge multi-head cosine mask: fp16 gather + f32 borderline recheck ============
__global__ __launch_bounds__(256)
void edge_kernel(const int* __restrict__ ei, int Edir,
                 const unsigned short* __restrict__ QKh, const float* __restrict__ QKf,
                 const float* __restrict__ cwts,
                 float* __restrict__ maskf, int* __restrict__ cnt, int Eund)
{
    int gid = blockIdx.x * 256 + threadIdx.x;
    int e = gid >> 3;
    if (e >= Eund) return;
    int sub = gid & 7;
    int row = ei[e];
    int col = ei[Edir + e];
    row = min(max(row, 0), N_NUM - 1);
    col = min(max(col, 0), N_NUM - 1);
    int u  = (row < U_NUM) ? row : col;
    int fg = (row < U_NUM) ? col : row;
    u = min(max(u, 0), U_NUM - 1);
    int f = min(max(fg - U_NUM, 0), F_NUM - 1);
    const size_t qrow = (size_t)u * D_EMB;
    const size_t krow = (size_t)(U_NUM + f) * D_EMB;

    const unsigned short* qh = QKh + qrow + sub * 16;
    const unsigned short* kh = QKh + krow + sub * 16;
    u16x8 qa = *(const u16x8*)(qh);
    u16x8 qb = *(const u16x8*)(qh + 8);
    u16x8 ka = *(const u16x8*)(kh);
    u16x8 kb = *(const u16x8*)(kh + 8);
    float dot = 0.f, qq = 0.f, kk = 0.f;
#pragma unroll
    for (int i = 0; i < 8; i++) {
        float qv = (float)__builtin_bit_cast(_Float16, (unsigned short)qa[i]);
        float kv = (float)__builtin_bit_cast(_Float16, (unsigned short)ka[i]);
        dot += qv * kv; qq += qv * qv; kk += kv * kv;
    }
#pragma unroll
    for (int i = 0; i < 8; i++) {
        float qv = (float)__builtin_bit_cast(_Float16, (unsigned short)qb[i]);
        float kv = (float)__builtin_bit_cast(_Float16, (unsigned short)kb[i]);
        dot += qv * kv; qq += qv * qv; kk += kv * kv;
    }
    dot += __shfl_xor(dot, 1);
    qq  += __shfl_xor(qq, 1);
    kk  += __shfl_xor(kk, 1);
    float denom = sqrtf(qq) * sqrtf(kk) + 1e-8f;
    float sim = dot / denom;
    float s = sim + __shfl_xor(sim, 2);
    s += __shfl_xor(s, 4);
    float mean = s * 0.25f;

    if (fabsf(mean - THRESH) < 0.03f) {
        const float4* qp = (const float4*)(QKf + qrow + sub * 16);
        const float4* kp = (const float4*)(QKf + krow + sub * 16);
        float dot2 = 0.f, qq2 = 0.f, kk2 = 0.f;
#pragma unroll
        for (int i = 0; i < 4; i++) {
            float4 a = qp[i]; float4 b = kp[i];
            dot2 += a.x * b.x + a.y * b.y + a.z * b.z + a.w * b.w;
            qq2  += a.x * a.x + a.y * a.y + a.z * a.z + a.w * a.w;
            kk2  += b.x * b.x + b.y * b.y + b.z * b.z + b.w * b.w;
        }
        dot2 += __shfl_xor(dot2, 1);
        qq2  += __shfl_xor(qq2, 1);
        kk2  += __shfl_xor(kk2, 1);
        float denom2 = sqrtf(qq2) * sqrtf(kk2) + 1e-8f;
        float sim2 = dot2 / denom2;
        float s2 = sim2 + __shfl_xor(sim2, 2);
        s2 += __shfl_xor(s2, 4);
        mean = s2 * 0.25f;
    }

    float mf = (mean > THRESH) ? 1.f : 0.f;
    float cw0 = cwts[0], cw1 = cwts[1];
    float mx = fmaxf(cw0, cw1);
    float e0 = expf(cw0 - mx), e1 = expf(cw1 - mx);
    float inv = 1.f / (e0 + e1);
    float fused = e0 * inv + (e1 * inv) * mf;
    float em = (fused > 0.5f) ? 1.f : 0.f;

    if (sub == 0) {
        maskf[e] = em;
        if (em != 0.f) {
            atomicAdd(&cnt[row], 1);
            atomicAdd(&cnt[col], 1);
        }
    }
}

// ============ exclusive scan over cnt[N] (3 kernels) ============
__global__ void scan_part(const int* __restrict__ cnt, int* __restrict__ part, int n)
{
    __shared__ int sd[256];
    int b = blockIdx.x, t = threadIdx.x;
    int base = b * 1024;
    int s = 0;
#pragma unroll
    for (int j = 0; j < 4; j++) {
        int idx = base + t + j * 256;
        if (idx < n) s += cnt[idx];
    }
    sd[t] = s; __syncthreads();
    for (int d = 128; d > 0; d >>= 1) {
        if (t < d) sd[t] += sd[t + d];
        __syncthreads();
    }
    if (t == 0) part[b] = sd[0];
}

__global__ void scan_small(int* part, int nb)
{
    __shared__ int sd[256];
    int t = threadIdx.x;
    sd[t] = (t < nb) ? part[t] : 0;
    __syncthreads();
    for (int d = 1; d < 256; d <<= 1) {
        int x = (t >= d) ? sd[t - d] : 0;
        __syncthreads();
        sd[t] += x;
        __syncthreads();
    }
    if (t < nb) part[t] = (t > 0) ? sd[t - 1] : 0;
}

__global__ void scan_final(const int* __restrict__ cnt, const int* __restrict__ part,
                           int* __restrict__ offs, int n)
{
    __shared__ int sd[256];
    int b = blockIdx.x, t = threadIdx.x;
    int base = b * 1024 + t * 4;
    int v[4]; int s = 0;
#pragma unroll
    for (int j = 0; j < 4; j++) {
        int idx = base + j;
        v[j] = (idx < n) ? cnt[idx] : 0;
        s += v[j];
    }
    sd[t] = s; __syncthreads();
    for (int d = 1; d < 256; d <<= 1) {
        int x = (t >= d) ? sd[t - d] : 0;
        __syncthreads();
        sd[t] += x;
        __syncthreads();
    }
    int prefix = part[b] + ((t > 0) ? sd[t - 1] : 0);
#pragma unroll
    for (int j = 0; j < 4; j++) {
        int idx = base + j;
        if (idx < n) offs[idx] = prefix;
        prefix += v[j];
    }
}

// ============ CSR scatter ============
__global__ void scatter_kernel(const int* __restrict__ ei, int Edir,
                               const float* __restrict__ maskf,
                               const int* __restrict__ cnt, const int* __restrict__ offs,
                               int* __restrict__ cursor,
                               int* __restrict__ cnbr, float* __restrict__ cwA, int Eund)
{
    int e = blockIdx.x * 256 + threadIdx.x;
    if (e >= Eund) return;
    if (maskf[e] == 0.f) return;
    int row = ei[e], col = ei[Edir + e];
    row = min(max(row, 0), N_NUM - 1);
    col = min(max(col, 0), N_NUM - 1);
    float w = 1.0f / sqrtf((float)cnt[row] * (float)cnt[col]);
    int p1 = offs[row] + atomicAdd(&cursor[row], 1);
    cnbr[p1] = col; cwA[p1] = w;
    int p2 = offs[col] + atomicAdd(&cursor[col], 1);
    cnbr[p2] = row; cwA[p2] = w;
}

// ============ propagation ============
template<int MODE>
__global__ __launch_bounds__(256)
void prop(const int* __restrict__ offs, const int* __restrict__ cnt,
          const int* __restrict__ cnbr, const float* __restrict__ cwA,
          const float* __restrict__ xin,
          const float* __restrict__ ue, const float* __restrict__ ie,
          const float* __restrict__ x1b, float* __restrict__ xout,
          float* __restrict__ tail)
{
    int wid = (blockIdx.x << 2) + (threadIdx.x >> 6);
    if (wid >= N_NUM) return;
    int lane = threadIdx.x & 63;
    int num = cnt[wid];
    if (MODE != 2 && num == 0) return;
    int start = (num > 0) ? offs[wid] : 0;
    float ax = 0.f, ay = 0.f;

    auto srcp = [&](int c) -> const float* {
        if (MODE == 0)
            return (c < U_NUM) ? (ue + (size_t)c * D_EMB) : (ie + (size_t)(c - U_NUM) * D_EMB);
        else
            return xin + (size_t)c * D_EMB;
    };

    int j = 0;
    for (; j + 4 <= num; j += 4) {
        int c0i = cnbr[start + j],     c1i = cnbr[start + j + 1];
        int c2i = cnbr[start + j + 2], c3i = cnbr[start + j + 3];
        float w0 = cwA[start + j],     w1 = cwA[start + j + 1];
        float w2 = cwA[start + j + 2], w3 = cwA[start + j + 3];
        float2 v0 = *(const float2*)(srcp(c0i) + lane * 2);
        float2 v1 = *(const float2*)(srcp(c1i) + lane * 2);
        float2 v2 = *(const float2*)(srcp(c2i) + lane * 2);
        float2 v3 = *(const float2*)(srcp(c3i) + lane * 2);
        ax += w0 * v0.x; ay += w0 * v0.y;
        ax += w1 * v1.x; ay += w1 * v1.y;
        ax += w2 * v2.x; ay += w2 * v2.y;
        ax += w3 * v3.x; ay += w3 * v3.y;
    }
    for (; j < num; ++j) {
        int c = cnbr[start + j]; float w = cwA[start + j];
        float2 v = *(const float2*)(srcp(c) + lane * 2);
        ax += w * v.x; ay += w * v.y;
    }

    size_t o = (size_t)wid * D_EMB + lane * 2;
    if (MODE == 2) {
        const float* x0p = (wid < U_NUM) ? (ue + (size_t)wid * D_EMB)
                                         : (ie + (size_t)(wid - U_NUM) * D_EMB);
        float2 x0v = *(const float2*)(x0p + lane * 2);
        *(float2*)(tail + o) = x0v;                     // embed copy (output tail)
        float ox, oy;
        if (num == 0) {
            ox = x0v.x * 0.25f; oy = x0v.y * 0.25f;
        } else {
            float2 x1v = *(const float2*)(x1b + o);
            float2 x2v = *(const float2*)(xin + o);
            ox = ((x0v.x + x1v.x) + x2v.x + ax) * 0.25f;
            oy = ((x0v.y + x1v.y) + x2v.y + ay) * 0.25f;
        }
        *(float2*)(xout + o) = make_float2(ox, oy);
    } else {
        *(float2*)(xout + o) = make_float2(ax, ay);
    }
}

// ============ launcher ============
extern "C" void kernel_launch(void* const* d_in, const int* in_sizes, int n_in,
                              void* d_out, int out_size, void* d_ws, size_t ws_size,
                              hipStream_t stream)
{
    const float* user_feat  = (const float*)d_in[0];
    const float* food_feat  = (const float*)d_in[1];
    const int*   ei         = (const int*)d_in[2];
    const float* W_user     = (const float*)d_in[3];
    const float* b_user     = (const float*)d_in[4];
    const float* W_food     = (const float*)d_in[5];
    const float* b_food     = (const float*)d_in[6];
    const float* Wq         = (const float*)d_in[7];
    const float* Wk         = (const float*)d_in[8];
    const float* cwts       = (const float*)d_in[9];
    const float* user_embed = (const float*)d_in[10];
    const float* item_embed = (const float*)d_in[11];

    const int Edir = in_sizes[2] / 2;   // 1.2M directed edges
    const int Eund = Edir / 2;          // 600K undirected ([u,f] || [f,u])

    char* ws = (char*)d_ws;
    size_t off = 0;
    auto alloc = [&](size_t nb) { size_t o = off; off += (nb + 255) & ~(size_t)255; return o; };

    float* Q     = (float*)(ws + alloc((size_t)N_NUM * D_EMB * 4));  // f32 Q|K -> xA
    float* xB    = (float*)(ws + alloc((size_t)N_NUM * D_EMB * 4));  // prop scratch
    unsigned short* QKh = (unsigned short*)(ws + alloc((size_t)N_NUM * D_EMB * 2));
    float* maskf = (float*)(ws + alloc((size_t)Eund * 4));
    int*   cnt   = (int*)  (ws + alloc((size_t)N_NUM * 4));
    int*   offs  = (int*)  (ws + alloc((size_t)N_NUM * 4));
    int*   cursor= (int*)  (ws + alloc((size_t)N_NUM * 4));
    int*   cnbr  = (int*)  (ws + alloc((size_t)Edir * 4));
    float* cwA   = (float*)(ws + alloc((size_t)Edir * 4));
    int*   part  = (int*)  (ws + alloc((size_t)256 * 4));
    unsigned short* Wsp = (unsigned short*)(ws + alloc((size_t)196608 * 2));
    (void)ws_size; (void)n_in; (void)out_size;

    float* xA = Q;   // N x 128, reuses Q|K after the edge stage

    // 1) pre-split weights + zero counters
    presplit_zero<<<384, 256, 0, stream>>>(W_user, W_food, Wq, Wk, Wsp, cnt, cursor);

    // 2) FUSED projection: Q = relu(feat@W1+b1)@W2, E stays in LDS
    fused_gemm<<<NBT_U + NBT_F, 256, 0, stream>>>(user_feat, food_feat, Wsp,
                                                  b_user, b_food, Q, QKh);

    // 3) per-edge mask + degree counts (fp16 gather, f32 borderline recheck)
    edge_kernel<<<(Eund * 8 + 255) / 256, 256, 0, stream>>>(ei, Edir, QKh, Q, cwts,
                                                            maskf, cnt, Eund);

    // 4) exclusive scan of cnt -> offs
    int nb = (N_NUM + 1023) / 1024;
    scan_part <<<nb, 256, 0, stream>>>(cnt, part, N_NUM);
    scan_small<<<1, 256, 0, stream>>>(part, nb);
    scan_final<<<nb, 256, 0, stream>>>(cnt, part, offs, N_NUM);

    // 5) CSR scatter
    scatter_kernel<<<(Eund + 255) / 256, 256, 0, stream>>>(ei, Edir, maskf, cnt, offs,
                                                           cursor, cnbr, cwA, Eund);

    // 6) three LightGCN layers; last fuses epilogue + embeds tail copy
    int pb = (N_NUM + 3) / 4;
    float* tail = (float*)d_out + (size_t)N_NUM * D_EMB;
    prop<0><<<pb, 256, 0, stream>>>(offs, cnt, cnbr, cwA, nullptr, user_embed, item_embed,
                                    nullptr, xB, nullptr);
    prop<1><<<pb, 256, 0, stream>>>(offs, cnt, cnbr, cwA, xB, user_embed, item_embed,
                                    nullptr, xA, nullptr);
    prop<2><<<pb, 256, 0, stream>>>(offs, cnt, cnbr, cwA, xA, user_embed, item_embed,
                                    xB, (float*)d_out, tail);
}